// Round 7
// baseline (640.289 us; speedup 1.0000x reference)
//
#include <hip/hip_runtime.h>

// Conv1dFFTInt8: B=16, CIN=128, COUT=128, L=4096, out_size==1.
// Identity: ifft(sum_l X[l]W[l])[0] = sum_n x[n] * w[(L-n) mod L]  (real inputs)
// => out[b,o] = bias[o] + sum_i sum_m w[o,i,m] * x[b,i,(L-m)&(L-1)]
//
// Ledger (R1-R3 visible dispatches): dur_us = conv + 267us harness const.
// R6 conv ~115us vs ~48us HBM floor. Theory: per-q pipeline bubbles -- wb
// issued+consumed in-phase, vmcnt(4) drains the CU queue to 64KB at every
// barrier, both blocks/CU barrier simultaneously -> burst/starve HBM.
// This round (T3/T4 deep pipeline): 16 chunks of 256 floats, 4 x-buffers
// (64KB LDS), weights prefetched one full chunk ahead (w never gates a
// barrier), staging issued TWO chunks ahead, vmcnt(12) at every barrier
// (12 loads/wave stay in flight across it). acc 64 + wc 16 + wn 16 ~= 106
// VGPR < 128 cap -> no spill at 2 blocks/CU.

constexpr int LEN   = 4096;
constexpr int CIN_  = 128;
constexpr int COUT_ = 128;
constexpr int BATCH = 16;

typedef float f32x4 __attribute__((ext_vector_type(4)));

__global__ void init_out_kernel(const float* __restrict__ bias, float* __restrict__ out) {
    int t = blockIdx.x * 256 + threadIdx.x;
    if (t < BATCH * COUT_) out[t] = bias[t & (COUT_ - 1)];
}

// Non-temporal 16B weight load: read-once stream, don't thrash L2 (x lives there).
__device__ __forceinline__ f32x4 ntload4(const float* p) {
    return __builtin_nontemporal_load((const f32x4*)p);
}

// Async 4B global->LDS. LDS dest is wave-uniform base; HW writes base+lane*4.
// The index reversal lives in the per-lane GLOBAL address; LDS stays linear.
__device__ __forceinline__ void gload_lds4(const float* g, float* l) {
    __builtin_amdgcn_global_load_lds(
        (const __attribute__((address_space(1))) unsigned int*)g,
        (__attribute__((address_space(3))) unsigned int*)l, 4, 0, 0);
}

// Wave wv stages its 2 batches for one 256-float chunk window starting at m0:
// lds_buf[b][u] = x[b, ci, (LEN - m0 - u) & 4095], u in [0,256). 8 gload_lds.
__device__ __forceinline__ void stage256(const float* xc0, const float* xc1,
                                         float* buf, int m0, int wv, int lane) {
    float* d0 = buf + ((2 * wv + 0) << 8);
    float* d1 = buf + ((2 * wv + 1) << 8);
#pragma unroll
    for (int t = 0; t < 4; ++t) {
        const int n = (LEN - m0 - (t << 6) - lane) & (LEN - 1);  // reversed source
        gload_lds4(xc0 + n, d0 + (t << 6));
        gload_lds4(xc1 + n, d1 + (t << 6));
    }
}

// Block: 512 threads = 8 waves, each wave 4 o-rows (32/block), ONE input
// channel. 16 K-chunks of 256. Grid = 4 o-tiles * 128 channels = 512 blocks,
// 2 blocks/CU (LDS 64KB). bk%8==ci%8: channel-sharing blocks co-XCD.
__global__ __launch_bounds__(512, 2)
void conv_fft_dot_kernel(const float* __restrict__ x, const float* __restrict__ w,
                         float* __restrict__ out) {
    // 64 KB: 4 x-buffers of 4096 floats. Epilogue (128 rows * 68) overlays.
    __shared__ float lds[16384];

    const int tid   = threadIdx.x;
    const int lane  = tid & 63;
    const int wv    = __builtin_amdgcn_readfirstlane(tid >> 6);
    const int bk    = blockIdx.x;
    const int ot    = bk >> 7;     // 0..3
    const int ci    = bk & 127;    // input channel
    const int obase = ot * 32 + wv * 4;

    const float* xc0 = x + (((2 * wv + 0) * CIN_ + ci) << 12);
    const float* xc1 = x + (((2 * wv + 1) * CIN_ + ci) << 12);
    const float* wr0 = w + (((obase + 0) * CIN_ + ci) << 12);
    const float* wr1 = w + (((obase + 1) * CIN_ + ci) << 12);
    const float* wr2 = w + (((obase + 2) * CIN_ + ci) << 12);
    const float* wr3 = w + (((obase + 3) * CIN_ + ci) << 12);
    const int lo = lane << 2;   // float offset of this lane's float4 in a chunk

    float acc[16][4];
#pragma unroll
    for (int b = 0; b < 16; ++b)
#pragma unroll
        for (int j = 0; j < 4; ++j) acc[b][j] = 0.f;

    // ---- prologue: stage chunks 0,1 (order pinned), weights for chunk 0.
    stage256(xc0, xc1, lds, 0, wv, lane);                 // 8 oldest vm ops
    __builtin_amdgcn_sched_barrier(0);
    stage256(xc0, xc1, lds + 4096, 256, wv, lane);
    __builtin_amdgcn_sched_barrier(0);
    f32x4 wc[4];
    wc[0] = ntload4(wr0 + lo); wc[1] = ntload4(wr1 + lo);
    wc[2] = ntload4(wr2 + lo); wc[3] = ntload4(wr3 + lo);
    asm volatile("s_waitcnt vmcnt(12)" ::: "memory");     // drain stage(0) only
    __builtin_amdgcn_s_barrier();
    __builtin_amdgcn_sched_barrier(0);

    // ---- main loop: 16 chunks, stepped by 4 so buffer indices are constants.
#pragma unroll 1
    for (int qq = 0; qq < 16; qq += 4) {
#define BODY(K)                                                               \
        {                                                                     \
            const int q  = qq + (K);                                          \
            const int m0 = q << 8;                                            \
            f32x4 wn[4];                                                      \
            if (q < 15) {   /* weights for chunk q+1: full phase of cover */  \
                wn[0] = ntload4(wr0 + m0 + 256 + lo);                         \
                wn[1] = ntload4(wr1 + m0 + 256 + lo);                         \
                wn[2] = ntload4(wr2 + m0 + 256 + lo);                         \
                wn[3] = ntload4(wr3 + m0 + 256 + lo);                         \
            }                                                                 \
            if (q < 14)     /* staging for chunk q+2: two phases of cover */  \
                stage256(xc0, xc1, lds + ((((K) + 2) & 3) << 12),             \
                         m0 + 512, wv, lane);                                 \
            __builtin_amdgcn_sched_barrier(0);                                \
            const float4* xb = (const float4*)(lds + (((K) & 3) << 12));      \
            _Pragma("unroll")                                                 \
            for (int b = 0; b < 16; ++b) {                                    \
                const float4 xv = xb[(b << 6) + lane];                        \
                _Pragma("unroll")                                             \
                for (int j = 0; j < 4; ++j) {                                 \
                    acc[b][j] += xv.x * wc[j].x;                              \
                    acc[b][j] += xv.y * wc[j].y;                              \
                    acc[b][j] += xv.z * wc[j].z;                              \
                    acc[b][j] += xv.w * wc[j].w;                              \
                }                                                             \
            }                                                                 \
            __builtin_amdgcn_sched_barrier(0);                                \
            if (q < 15) {                                                     \
                wc[0] = wn[0]; wc[1] = wn[1]; wc[2] = wn[2]; wc[3] = wn[3];   \
            }                                                                 \
            if (q < 14)                                                       \
                asm volatile("s_waitcnt vmcnt(12)" ::: "memory");             \
            else if (q == 14)                                                 \
                asm volatile("s_waitcnt vmcnt(4)" ::: "memory");              \
            if (q < 15) {                                                     \
                __builtin_amdgcn_s_barrier();                                 \
                __builtin_amdgcn_sched_barrier(0);                            \
            }                                                                 \
        }
        BODY(0) BODY(1) BODY(2) BODY(3)
#undef BODY
    }

    // ---- cross-lane reduction via padded LDS transpose, 4 static passes
    // (rule #20: every acc index compile-time). 128 rows * 68 floats/pass.
    __syncthreads();
#pragma unroll
    for (int p = 0; p < 4; ++p) {
        if (p) __syncthreads();
#pragma unroll
        for (int bb = 0; bb < 4; ++bb)
#pragma unroll
            for (int j = 0; j < 4; ++j)
                lds[(wv * 16 + bb * 4 + j) * 68 + lane] = acc[p * 4 + bb][j];
        __syncthreads();
        if (tid < 128) {
            const float4* row = (const float4*)(lds + tid * 68);  // 272B aligned
            float sum = 0.f;
#pragma unroll
            for (int l = 0; l < 16; ++l) {
                const float4 v = row[l];
                sum += v.x + v.y + v.z + v.w;
            }
            const int o = ot * 32 + (tid >> 4) * 4 + (tid & 3);
            const int b = p * 4 + ((tid >> 2) & 3);
            atomicAdd(out + b * COUT_ + o, sum);
        }
    }
}

extern "C" void kernel_launch(void* const* d_in, const int* in_sizes, int n_in,
                              void* d_out, int out_size, void* d_ws, size_t ws_size,
                              hipStream_t stream) {
    const float* x    = (const float*)d_in[0];   // [16,128,4096]
    const float* wgt  = (const float*)d_in[1];   // [128,128,4096]
    const float* bias = (const float*)d_in[2];   // [128]
    float* out = (float*)d_out;                  // [16,128,1]
    (void)in_sizes; (void)n_in; (void)d_ws; (void)ws_size; (void)out_size;

    init_out_kernel<<<8, 256, 0, stream>>>(bias, out);
    conv_fft_dot_kernel<<<512, 512, 0, stream>>>(x, wgt, out);
}

// Round 8
// 372.742 us; speedup vs baseline: 1.7178x; 1.7178x over previous
//
#include <hip/hip_runtime.h>

// Conv1dFFTInt8: B=16, CIN=128, COUT=128, L=4096, out_size==1.
// Identity: ifft(sum_l X[l]W[l])[0] = sum_n x[n] * w[(L-n) mod L]  (real inputs)
// => out[b,o] = bias[o] + sum_i sum_m w[o,i,m] * x[b,i,(L-m)&(L-1)]
//
// Ledger: dur_us = conv + 267us harness const (R1-R3 visible dispatches).
// R6 best: conv ~115us vs ~48us floor (268MB weights + 32MB x @6.3TB/s).
// R7 (4-deep pipeline) spilled: fences pinned >128 live VGPRs. Lesson: the
// register budget here is ~118; schedules needing more are DOA.
// This round: attack the barrier-drain oscillation with TLP, not depth.
// 256-thread blocks (4 waves), chunk=256, x-dbuf = 32KB LDS only (epilogue
// overlays dead buffers) -> 4 independent barrier groups per CU (was 2).
// Register shape = R6's proven one: acc[16][4] + wcA[4]/wcB[4], no copies
// (even/odd phases statically alternate). vmcnt(4) at each barrier keeps
// exactly the 4 next-chunk weight loads in flight (order pinned by fences
// BETWEEN load classes only). Grid 1024 = exactly 4 blocks/CU, one wave.

constexpr int LEN   = 4096;
constexpr int CIN_  = 128;
constexpr int COUT_ = 128;
constexpr int BATCH = 16;

typedef float f32x4 __attribute__((ext_vector_type(4)));

__global__ void init_out_kernel(const float* __restrict__ bias, float* __restrict__ out) {
    int t = blockIdx.x * 256 + threadIdx.x;
    if (t < BATCH * COUT_) out[t] = bias[t & (COUT_ - 1)];
}

// Non-temporal 16B weight load: read-once stream, keep L2 for x.
__device__ __forceinline__ f32x4 ntload4(const float* p) {
    return __builtin_nontemporal_load((const f32x4*)p);
}

// Async 4B global->LDS. LDS dest is wave-uniform base (+lane*4 in HW);
// the index reversal lives in the per-lane GLOBAL address.
__device__ __forceinline__ void gload_lds4(const float* g, float* l) {
    __builtin_amdgcn_global_load_lds(
        (const __attribute__((address_space(1))) unsigned int*)g,
        (__attribute__((address_space(3))) unsigned int*)l, 4, 0, 0);
}

// Wave wv stages batches 4wv..4wv+3 for one 256-float chunk at m0:
// buf[b*256 + u] = x[b, ci, (LEN - m0 - u) & 4095], u in [0,256). 16 gloads.
#define STAGE(BUF, M0)                                                     \
    {                                                                      \
        _Pragma("unroll")                                                  \
        for (int t = 0; t < 4; ++t) {                                      \
            const int n = (LEN - (M0) - (t << 6) - lane) & (LEN - 1);      \
            gload_lds4(xc0 + n, (BUF) + ((4 * wv + 0) << 8) + (t << 6));   \
            gload_lds4(xc1 + n, (BUF) + ((4 * wv + 1) << 8) + (t << 6));   \
            gload_lds4(xc2 + n, (BUF) + ((4 * wv + 2) << 8) + (t << 6));   \
            gload_lds4(xc3 + n, (BUF) + ((4 * wv + 3) << 8) + (t << 6));   \
        }                                                                  \
    }

// 256 FMAs against one chunk: 16 ds_read_b128, weight regs WC[0..3] (static).
#define COMPUTE(BUF, WC)                                                   \
    {                                                                      \
        const float4* xb = (const float4*)(BUF);                           \
        _Pragma("unroll")                                                  \
        for (int b = 0; b < 16; ++b) {                                     \
            const float4 xv = xb[(b << 6) + lane];                         \
            _Pragma("unroll")                                              \
            for (int j = 0; j < 4; ++j) {                                  \
                acc[b][j] += xv.x * WC[j].x;                               \
                acc[b][j] += xv.y * WC[j].y;                               \
                acc[b][j] += xv.z * WC[j].z;                               \
                acc[b][j] += xv.w * WC[j].w;                               \
            }                                                              \
        }                                                                  \
    }

// Block: 256 threads = 4 waves, each wave 4 o-rows (16/block), ONE channel,
// 16 chunks of 256. Grid = 8 ot * 128 ci = 1024 = 4 blocks/CU, one pass.
// bk%8==ci%8: the 8 ot-siblings sharing a channel land on one XCD.
// __launch_bounds__(256,2): empirical hipcc VGPR cap = 256/arg = 128.
__global__ __launch_bounds__(256, 2)
void conv_fft_dot_kernel(const float* __restrict__ x, const float* __restrict__ w,
                         float* __restrict__ out) {
    // 32 KB total: two 16KB x-buffers; epilogue (64 rows * 68) overlays buf0.
    __shared__ float lds[8192];

    const int tid   = threadIdx.x;
    const int lane  = tid & 63;
    const int wv    = __builtin_amdgcn_readfirstlane(tid >> 6);
    const int bk    = blockIdx.x;
    const int ot    = bk >> 7;     // 0..7
    const int ci    = bk & 127;    // input channel
    const int obase = ot * 16 + wv * 4;

    // wave-uniform bases (SGPR): per-lane part stays a shared 32-bit offset
    const float* xc0 = x + (((4 * wv + 0) * CIN_ + ci) << 12);
    const float* xc1 = x + (((4 * wv + 1) * CIN_ + ci) << 12);
    const float* xc2 = x + (((4 * wv + 2) * CIN_ + ci) << 12);
    const float* xc3 = x + (((4 * wv + 3) * CIN_ + ci) << 12);
    const float* wr0 = w + (((obase + 0) * CIN_ + ci) << 12);
    const float* wr1 = w + (((obase + 1) * CIN_ + ci) << 12);
    const float* wr2 = w + (((obase + 2) * CIN_ + ci) << 12);
    const float* wr3 = w + (((obase + 3) * CIN_ + ci) << 12);
    const int lo = lane << 2;   // float offset of this lane's float4 in a chunk

    float acc[16][4];
#pragma unroll
    for (int b = 0; b < 16; ++b)
#pragma unroll
        for (int j = 0; j < 4; ++j) acc[b][j] = 0.f;

    f32x4 wcA[4], wcB[4];

    // ---- prologue: stage chunk 0, then chunk-0 weights (the 4 newest vm ops)
    STAGE(lds, 0)
    __builtin_amdgcn_sched_barrier(0);           // stage strictly before weights
    wcA[0] = ntload4(wr0 + lo); wcA[1] = ntload4(wr1 + lo);
    wcA[2] = ntload4(wr2 + lo); wcA[3] = ntload4(wr3 + lo);
    asm volatile("s_waitcnt vmcnt(4)" ::: "memory");  // drain stage(0), keep wcA
    __builtin_amdgcn_s_barrier();
    __builtin_amdgcn_sched_barrier(0);

    // ---- 16 chunks, 2-phase unrolled: even->buf0/wcA, odd->buf1/wcB.
#pragma unroll 1
    for (int qq = 0; qq < 16; qq += 2) {
        {   // even phase q = qq (q <= 14: always prefetches q+1)
            const int m0 = qq << 8;
            STAGE(lds + 4096, m0 + 256)
            __builtin_amdgcn_sched_barrier(0);   // stage before weight loads
            wcB[0] = ntload4(wr0 + m0 + 256 + lo);
            wcB[1] = ntload4(wr1 + m0 + 256 + lo);
            wcB[2] = ntload4(wr2 + m0 + 256 + lo);
            wcB[3] = ntload4(wr3 + m0 + 256 + lo);
            __builtin_amdgcn_sched_barrier(0);   // loads issued before compute
            COMPUTE(lds, wcA)
            asm volatile("s_waitcnt vmcnt(4)" ::: "memory");  // drain stage(q+1), keep wcB
            __builtin_amdgcn_s_barrier();
            __builtin_amdgcn_sched_barrier(0);
        }
        {   // odd phase q = qq+1 (skips prefetch when q == 15)
            const int q  = qq + 1;
            const int m0 = q << 8;
            if (q < 15) {
                STAGE(lds, m0 + 256)
                __builtin_amdgcn_sched_barrier(0);
                wcA[0] = ntload4(wr0 + m0 + 256 + lo);
                wcA[1] = ntload4(wr1 + m0 + 256 + lo);
                wcA[2] = ntload4(wr2 + m0 + 256 + lo);
                wcA[3] = ntload4(wr3 + m0 + 256 + lo);
            }
            __builtin_amdgcn_sched_barrier(0);
            COMPUTE(lds + 4096, wcB)
            if (q < 15) {
                asm volatile("s_waitcnt vmcnt(4)" ::: "memory");
                __builtin_amdgcn_s_barrier();
                __builtin_amdgcn_sched_barrier(0);
            }
        }
    }

    // ---- epilogue: cross-lane sum via padded LDS transpose in the dead
    // x-buffer (64 rows * 68 floats = 17KB <= 32KB). 4 fully-static passes
    // (rule #20: every acc index compile-time).
    __syncthreads();
#pragma unroll
    for (int p = 0; p < 4; ++p) {
        if (p) __syncthreads();
#pragma unroll
        for (int bb = 0; bb < 4; ++bb)
#pragma unroll
            for (int j = 0; j < 4; ++j)
                lds[(wv * 16 + bb * 4 + j) * 68 + lane] = acc[p * 4 + bb][j];
        __syncthreads();
        if (tid < 64) {
            const float4* row = (const float4*)(lds + tid * 68);  // 272B: 16B-aligned
            float sum = 0.f;
#pragma unroll
            for (int l = 0; l < 16; ++l) {
                const float4 v = row[l];
                sum += v.x + v.y + v.z + v.w;
            }
            const int o = ot * 16 + (tid >> 4) * 4 + (tid & 3);
            const int b = p * 4 + ((tid >> 2) & 3);
            atomicAdd(out + b * COUT_ + o, sum);
        }
    }
}

extern "C" void kernel_launch(void* const* d_in, const int* in_sizes, int n_in,
                              void* d_out, int out_size, void* d_ws, size_t ws_size,
                              hipStream_t stream) {
    const float* x    = (const float*)d_in[0];   // [16,128,4096]
    const float* wgt  = (const float*)d_in[1];   // [128,128,4096]
    const float* bias = (const float*)d_in[2];   // [128]
    float* out = (float*)d_out;                  // [16,128,1]
    (void)in_sizes; (void)n_in; (void)d_ws; (void)ws_size; (void)out_size;

    init_out_kernel<<<8, 256, 0, stream>>>(bias, out);
    conv_fft_dot_kernel<<<1024, 256, 0, stream>>>(x, wgt, out);
}